// Round 1
// baseline (608.636 us; speedup 1.0000x reference)
//
#include <hip/hip_runtime.h>
#include <math.h>

#define BB 2
#define SS 2048
#define NN 2049
#define MM (BB*NN)      // 4098 rows
#define DD 256
#define HR 128          // HEADS*RANK
#define NHEAD 4
#define WINW 64
#define KW 129          // 2*WIN+1
#define DFF 512
#define EPSF 1e-6f

// ---------- reduction helpers (256-thread blocks, wave=64) ----------
__device__ __forceinline__ float wave_sum(float v) {
    v += __shfl_down(v, 32, 64);
    v += __shfl_down(v, 16, 64);
    v += __shfl_down(v, 8, 64);
    v += __shfl_down(v, 4, 64);
    v += __shfl_down(v, 2, 64);
    v += __shfl_down(v, 1, 64);
    return v;
}
__device__ __forceinline__ float wave_max(float v) {
    v = fmaxf(v, __shfl_down(v, 32, 64));
    v = fmaxf(v, __shfl_down(v, 16, 64));
    v = fmaxf(v, __shfl_down(v, 8, 64));
    v = fmaxf(v, __shfl_down(v, 4, 64));
    v = fmaxf(v, __shfl_down(v, 2, 64));
    v = fmaxf(v, __shfl_down(v, 1, 64));
    return v;
}
__device__ __forceinline__ float block_sum(float v, float* red) {
    v = wave_sum(v);
    __syncthreads();
    if ((threadIdx.x & 63) == 0) red[threadIdx.x >> 6] = v;
    __syncthreads();
    return red[0] + red[1] + red[2] + red[3];
}
__device__ __forceinline__ float block_max(float v, float* red) {
    v = wave_max(v);
    __syncthreads();
    if ((threadIdx.x & 63) == 0) red[threadIdx.x >> 6] = v;
    __syncthreads();
    return fmaxf(fmaxf(red[0], red[1]), fmaxf(red[2], red[3]));
}
__device__ __forceinline__ float sgnf(float x) {
    return (x > 0.f) ? 1.f : ((x < 0.f) ? -1.f : 0.f);
}

// ---------- embed: tok = emb[id]+pos; val=unit(tok); state=tok@Ws+bs ----------
__global__ void embed_kernel(const int* __restrict__ ids,
                             const float* __restrict__ emb,
                             const float* __restrict__ pos,
                             const float* __restrict__ anchor_val,
                             const float* __restrict__ anchor_state,
                             const float* __restrict__ Ws,
                             const float* __restrict__ bs,
                             float* __restrict__ val,
                             float* __restrict__ state) {
    __shared__ float red[4];
    int row = blockIdx.x;           // 0..MM-1
    int t = threadIdx.x;            // 0..255 == d
    int b = row / NN, n = row % NN;
    float e;
    if (n == 0) {
        e = anchor_val[t];
    } else {
        int id = ids[b * SS + (n - 1)];
        e = emb[id * DD + t] + pos[(n - 1) * DD + t];
    }
    float ss = block_sum(e * e, red);
    float ts = block_sum(e * Ws[t], red);
    float rn = 1.f / fmaxf(sqrtf(ss), EPSF);
    val[row * DD + t] = e * rn;
    if (t == 0) state[row] = (n == 0) ? anchor_state[0] : (ts + bs[0]);
}

// ---------- q/k projection, 8-token tile ----------
__global__ void proj_kernel(const float* __restrict__ val,
                            const float* __restrict__ U,   // layer base, (D,128)
                            const float* __restrict__ V,
                            float* __restrict__ q,
                            float* __restrict__ k) {
    __shared__ float vT[DD][8];   // [d][m], 8 KB, 32B rows
    int m0 = blockIdx.x * 8;
    int t = threadIdx.x;
    #pragma unroll
    for (int m = 0; m < 8; m++) {
        int row = m0 + m;
        vT[t][m] = (row < MM) ? val[row * DD + t] : 0.f;
    }
    __syncthreads();
    const float* Wm = (t < HR) ? U : V;
    int o = t & 127;
    float acc[8];
    #pragma unroll
    for (int m = 0; m < 8; m++) acc[m] = 0.f;
    for (int d = 0; d < DD; d++) {
        float w = Wm[d * HR + o];
        const float* vp = &vT[d][0];
        #pragma unroll
        for (int m = 0; m < 8; m++) acc[m] += vp[m] * w;
    }
    float* outp = (t < HR) ? q : k;
    #pragma unroll
    for (int m = 0; m < 8; m++) {
        int row = m0 + m;
        if (row < MM) outp[row * HR + o] = acc[m];
    }
}

// ---------- windowed signed-softmax attention, per-token block ----------
__global__ void attn_kernel(const float* __restrict__ val_in,
                            const float* __restrict__ state_in,
                            const float* __restrict__ q,
                            const float* __restrict__ k,
                            float* __restrict__ val_out,
                            float* __restrict__ dstate_out) {
    __shared__ float qs[HR];
    __shared__ float wgt[KW];
    __shared__ float red[4];
    int row = blockIdx.x;
    int b = row / NN, n = row % NN;
    int t = threadIdx.x;
    if (t < HR) qs[t] = q[row * HR + t];
    __syncthreads();

    float s_val = 0.f;
    bool valid = false;
    if (t < KW) {
        int j = n - WINW + t;
        if (j >= 0 && j < NN) {
            valid = true;
            const float4* kr = (const float4*)&k[(b * NN + j) * HR];
            float smax_h = -INFINITY;
            #pragma unroll
            for (int h = 0; h < NHEAD; h++) {
                float acc = 0.f;
                #pragma unroll
                for (int i = 0; i < 8; i++) {
                    float4 kv = kr[h * 8 + i];
                    float4 qv = *(const float4*)&qs[h * 32 + i * 4];
                    acc += kv.x * qv.x + kv.y * qv.y + kv.z * qv.z + kv.w * qv.w;
                }
                smax_h = fmaxf(smax_h, acc);
            }
            s_val = smax_h * 0.17677669529663687f;  // 1/sqrt(32)
        }
    }
    float a = valid ? fabsf(s_val) : -INFINITY;
    float mx = block_max(a, red);
    float e = valid ? expf(fabsf(s_val) - mx) : 0.f;
    float sum = block_sum(e, red);
    float wv = valid ? sgnf(s_val) * e / sum : 0.f;
    if (t < KW) wgt[t] = wv;
    // dstate = sum_k w * state[j]
    float dsp = valid ? wv * state_in[b * NN + (n - WINW + t)] : 0.f;
    float dsum = block_sum(dsp, red);
    if (t == 0) dstate_out[row] = dsum;
    __syncthreads();  // wgt visible

    // dval[d=t] = sum_j wgt * val_in[b,j,d]
    float acc = 0.f;
    int lo = (n - WINW > 0) ? (n - WINW) : 0;
    int hi = (n + WINW < NN - 1) ? (n + WINW) : (NN - 1);
    const float* vbase = val_in + b * NN * DD + t;
    for (int j = lo; j <= hi; j++) {
        acc += wgt[j - n + WINW] * vbase[j * DD];
    }
    float vold = val_in[row * DD + t];
    float upd = vold + acc;
    float mab = block_max(fabsf(acc), red);
    float ss = block_sum(upd * upd, red);
    float rn = 1.f / fmaxf(sqrtf(ss), EPSF);
    val_out[row * DD + t] = (mab > 0.f) ? upd * rn : upd;
}

// ---------- state update: signed softmax over N per batch row ----------
__global__ void state_kernel(const float* __restrict__ state_in,
                             const float* __restrict__ dstate,
                             float* __restrict__ state_out) {
    __shared__ float xs[NN];
    __shared__ float red[4];
    int b = blockIdx.x, t = threadIdx.x;
    float lmax = -INFINITY;
    for (int n = t; n < NN; n += 256) {
        float x = state_in[b * NN + n] + dstate[b * NN + n];
        xs[n] = x;
        lmax = fmaxf(lmax, fabsf(x));
    }
    float m = block_max(lmax, red);
    float lsum = 0.f;
    for (int n = t; n < NN; n += 256) lsum += expf(fabsf(xs[n]) - m);
    float ssum = block_sum(lsum, red);
    float inv = 1.f / ssum;
    for (int n = t; n < NN; n += 256) {
        float x = xs[n];
        state_out[b * NN + n] = sgnf(x) * expf(fabsf(x) - m) * inv;
    }
}

// ---------- FFN: val = unit(val + gelu(val@W1+b1)@W2 + b2), 8-token tile ----------
__global__ void ffn_kernel(const float* __restrict__ val_in,
                           const float* __restrict__ W1,   // (D, 2D)
                           const float* __restrict__ b1,   // (2D)
                           const float* __restrict__ W2,   // (2D, D)
                           const float* __restrict__ b2,   // (D)
                           float* __restrict__ val_out) {
    __shared__ float vT[DD][8];    // 8 KB
    __shared__ float hT[DFF][8];   // 16 KB
    __shared__ float red[4];
    int m0 = blockIdx.x * 8;
    int t = threadIdx.x;
    #pragma unroll
    for (int m = 0; m < 8; m++) {
        int row = m0 + m;
        vT[t][m] = (row < MM) ? val_in[row * DD + t] : 0.f;
    }
    __syncthreads();
    // GEMM1: h[o=t] and h[o=t+256]
    float acc0[8], acc1[8];
    #pragma unroll
    for (int m = 0; m < 8; m++) { acc0[m] = 0.f; acc1[m] = 0.f; }
    for (int d = 0; d < DD; d++) {
        float w0 = W1[d * DFF + t];
        float w1 = W1[d * DFF + t + 256];
        const float* vp = &vT[d][0];
        #pragma unroll
        for (int m = 0; m < 8; m++) {
            float vv = vp[m];
            acc0[m] += vv * w0;
            acc1[m] += vv * w1;
        }
    }
    float bb0 = b1[t], bb1 = b1[t + 256];
    #pragma unroll
    for (int m = 0; m < 8; m++) {
        float x0 = acc0[m] + bb0;
        float x1 = acc1[m] + bb1;
        hT[t][m]       = 0.5f * x0 * (1.f + erff(x0 * 0.70710678118654752f));
        hT[t + 256][m] = 0.5f * x1 * (1.f + erff(x1 * 0.70710678118654752f));
    }
    __syncthreads();
    // GEMM2: out[d=t]
    float acc2[8];
    #pragma unroll
    for (int m = 0; m < 8; m++) acc2[m] = 0.f;
    for (int j = 0; j < DFF; j++) {
        float w = W2[j * DD + t];
        const float* hp = &hT[j][0];
        #pragma unroll
        for (int m = 0; m < 8; m++) acc2[m] += hp[m] * w;
    }
    float bb = b2[t];
    for (int m = 0; m < 8; m++) {   // uniform trip, contains barriers
        int row = m0 + m;
        float y = vT[t][m] + acc2[m] + bb;
        float ss = block_sum(y * y, red);
        if (row < MM) {
            float rn = 1.f / fmaxf(sqrtf(ss), EPSF);
            val_out[row * DD + t] = y * rn;
        }
    }
}

extern "C" void kernel_launch(void* const* d_in, const int* in_sizes, int n_in,
                              void* d_out, int out_size, void* d_ws, size_t ws_size,
                              hipStream_t stream) {
    const int*   ids          = (const int*)d_in[0];
    const float* emb          = (const float*)d_in[1];
    const float* pos          = (const float*)d_in[2];
    const float* anchor_val   = (const float*)d_in[3];
    const float* anchor_state = (const float*)d_in[4];
    const float* Ws           = (const float*)d_in[5];
    const float* bs           = (const float*)d_in[6];
    const float* U            = (const float*)d_in[7];
    const float* V            = (const float*)d_in[8];
    const float* W1           = (const float*)d_in[9];
    const float* b1           = (const float*)d_in[10];
    const float* W2           = (const float*)d_in[11];
    const float* b2           = (const float*)d_in[12];
    float* out = (float*)d_out;

    float* w    = (float*)d_ws;
    float* valA = w;
    float* valB = valA + MM * DD;
    float* qbuf = valB + MM * DD;
    float* kbuf = qbuf + MM * HR;
    float* st0  = kbuf + MM * HR;
    float* st1  = st0 + MM;
    float* dst  = st1 + MM;

    embed_kernel<<<MM, 256, 0, stream>>>(ids, emb, pos, anchor_val, anchor_state,
                                         Ws, bs, valA, st0);
    float* s_in = st0;
    float* s_out = st1;
    for (int l = 0; l < 3; l++) {
        proj_kernel<<<(MM + 7) / 8, 256, 0, stream>>>(
            valA, U + l * DD * HR, V + l * DD * HR, qbuf, kbuf);
        attn_kernel<<<MM, 256, 0, stream>>>(valA, s_in, qbuf, kbuf, valB, dst);
        state_kernel<<<BB, 256, 0, stream>>>(s_in, dst, (l == 2) ? out : s_out);
        ffn_kernel<<<(MM + 7) / 8, 256, 0, stream>>>(
            valB, W1 + l * DD * DFF, b1 + l * DFF, W2 + l * DFF * DD, b2 + l * DD,
            (l == 2) ? (out + MM) : valA);
        float* tmp = s_in; s_in = s_out; s_out = tmp;
    }
}